// Round 12
// baseline (166.678 us; speedup 1.0000x reference)
//
#include <hip/hip_runtime.h>

#define NFEAT 64
#define BNODES 64            // nodes per dst-bucket (bucket = dst >> 6)
#define MAXBUCK 1024         // supports N <= 65536 (edge packing needs N <= 65536)
#define SORT_LDS 6144        // whole-bucket LDS staging for in-place sort path
#define KPT 4                // edges per thread in k_part (register-staged)

__device__ __forceinline__ int load_idx(const int* __restrict__ ei, long long elem, int is64) {
    return is64 ? ei[2 * elem] : ei[(int)elem];
}

// bf16 round-to-nearest-even-ish (RN with tie bump; fine for finite data)
__device__ __forceinline__ unsigned short f2bf(float f) {
    unsigned int u = __float_as_uint(f);
    return (unsigned short)((u + 0x7FFFu + ((u >> 16) & 1u)) >> 16);
}
__device__ __forceinline__ float bf2f(unsigned short h) {
    return __uint_as_float(((unsigned int)h) << 16);
}

// ------- bucket-level histogram (782 counters; LDS hist + merge) ------------
// Self-detects int64 vs int32 edge encoding: values < 65536, so under int64
// every odd int32 word is 0 (probe 256 odd words; all-zero => int64).
__global__ __launch_bounds__(256) void k_histb(
        const int* __restrict__ ei, int* __restrict__ bcnt, int E, int nb) {
    __shared__ int h[MAXBUCK];
    __shared__ int s_not64;
    if (threadIdx.x == 0) s_not64 = 0;
    for (int i = threadIdx.x; i < nb; i += 256) h[i] = 0;
    __syncthreads();
    if (ei[2 * threadIdx.x + 1] != 0) s_not64 = 1;   // benign same-value race
    __syncthreads();
    int is64 = s_not64 ? 0 : 1;
    int per = (E + gridDim.x - 1) / gridDim.x;
    int e0 = blockIdx.x * per;
    int e1 = min(e0 + per, E);
    for (int i = e0 + threadIdx.x; i < e1; i += 256) {
        int d = load_idx(ei, (long long)E + i, is64);
        atomicAdd(&h[d >> 6], 1);
    }
    __syncthreads();
    for (int i = threadIdx.x; i < nb; i += 256)
        if (h[i]) atomicAdd(&bcnt[i], h[i]);
}

// ------- exclusive scan of bucket counts (+ sentinel) ------------------------
__global__ void k_bscan(const int* __restrict__ bcnt, int* __restrict__ bstart,
                        int* __restrict__ bfill, int nb, int E) {
    __shared__ int s[1024];
    int t = threadIdx.x;
    int mine = (t < nb) ? bcnt[t] : 0;
    s[t] = mine;
    __syncthreads();
    for (int off = 1; off < 1024; off <<= 1) {
        int v = (t >= off) ? s[t - off] : 0;
        __syncthreads();
        s[t] += v;
        __syncthreads();
    }
    if (t < nb) {
        int excl = s[t] - mine;
        bstart[t] = excl;
        bfill[t] = excl;
    }
    if (t == 0) bstart[nb] = E;   // sentinel
}

// ------- partition edges into dst-buckets, packed as (dst<<16)|src -----------
// Register-staged: each thread owns <= KPT edges, packs them once (no second
// global read of edge_index). 3-phase: LDS hist -> reserve chunks -> scatter.
__global__ __launch_bounds__(1024) void k_part(
        const int* __restrict__ ei, int* __restrict__ bfill,
        unsigned int* __restrict__ edges, int E, int nb) {
    __shared__ int h[MAXBUCK];
    __shared__ int chunk[MAXBUCK];
    __shared__ int cur[MAXBUCK];
    __shared__ int s_not64;
    if (threadIdx.x == 0) s_not64 = 0;
    for (int i = threadIdx.x; i < nb; i += 1024) h[i] = 0;
    __syncthreads();
    if (threadIdx.x < 256 && ei[2 * threadIdx.x + 1] != 0) s_not64 = 1;
    __syncthreads();
    int is64 = s_not64 ? 0 : 1;
    int per = (E + gridDim.x - 1) / gridDim.x;   // per <= 1024*KPT by grid calc
    int e0 = blockIdx.x * per;
    int e1 = min(e0 + per, E);

    unsigned int ed[KPT];
#pragma unroll
    for (int k = 0; k < KPT; ++k) {
        int i = e0 + threadIdx.x + k * 1024;
        if (i < e1) {
            unsigned int s = (unsigned int)load_idx(ei, i, is64);
            unsigned int d = (unsigned int)load_idx(ei, (long long)E + i, is64);
            ed[k] = (d << 16) | s;
            atomicAdd(&h[d >> 6], 1);
        }
    }
    __syncthreads();
    for (int i = threadIdx.x; i < nb; i += 1024) {
        int c = h[i];
        chunk[i] = c ? atomicAdd(&bfill[i], c) : 0;
        cur[i] = 0;
    }
    __syncthreads();
#pragma unroll
    for (int k = 0; k < KPT; ++k) {
        int i = e0 + threadIdx.x + k * 1024;
        if (i < e1) {
            int b = (int)(ed[k] >> 22);          // = dst >> 6
            int r = atomicAdd(&cur[b], 1);
            edges[chunk[b] + r] = ed[k];
        }
    }
}

// ------- per-bucket counting sort into ushort CSR + per-node count/ptr -------
// One block per bucket. LDS histogram doubles as per-node degree (count[v])
// and, scanned, as the CSR row pointer (ptr[v]).
template <bool INPLACE>
__global__ __launch_bounds__(256) void k_sort2(
        const unsigned int* __restrict__ edges, const int* __restrict__ bstart,
        int* __restrict__ count, int* __restrict__ ptr,
        unsigned short* __restrict__ sorted_src, int N, int E) {
    __shared__ int cnt64[BNODES];
    __shared__ int pos64[BNODES];
    __shared__ unsigned int raw[INPLACE ? SORT_LDS : 1];
    int tid = threadIdx.x;
    int vbase = blockIdx.x * BNODES;
    int es = bstart[blockIdx.x];
    int ee = bstart[blockIdx.x + 1];
    int m = ee - es;
    if (tid < BNODES) cnt64[tid] = 0;
    __syncthreads();

    if (INPLACE) {
        int mm = min(m, SORT_LDS);
        for (int i = tid; i < mm; i += 256) {
            unsigned int e = edges[es + i];
            raw[i] = e;
            atomicAdd(&cnt64[(e >> 16) & 63u], 1);
        }
        for (int i = SORT_LDS + tid; i < m; i += 256)
            atomicAdd(&cnt64[(edges[es + i] >> 16) & 63u], 1);
    } else {
        for (int i = tid; i < m; i += 256)
            atomicAdd(&cnt64[(edges[es + i] >> 16) & 63u], 1);
    }
    __syncthreads();

    if (tid < BNODES) {                      // wave 0: 64-wide exclusive scan
        int c = cnt64[tid];
        int inc = c;
#pragma unroll
        for (int d = 1; d < 64; d <<= 1) {
            int t2 = __shfl_up(inc, d, 64);
            if (tid >= d) inc += t2;
        }
        int off = inc - c;
        pos64[tid] = es + off;
        int v = vbase + tid;
        if (v < N) {
            count[v] = c;
            ptr[v] = es + off;
        }
    }
    __syncthreads();

    if (INPLACE) {
        int mm = min(m, SORT_LDS);
        for (int i = tid; i < mm; i += 256) {
            unsigned int e = raw[i];
            int p = atomicAdd(&pos64[(e >> 16) & 63u], 1);
            sorted_src[p] = (unsigned short)(e & 0xFFFFu);
        }
        for (int i = SORT_LDS + tid; i < m; i += 256) {   // overflow: ~never
            unsigned int e = edges[es + i];
            int p = atomicAdd(&pos64[(e >> 16) & 63u], 1);
            sorted_src[p] = (unsigned short)(e & 0xFFFFu);
        }
    } else {
        for (int i = tid; i < m; i += 256) {
            unsigned int e = edges[es + i];
            int p = atomicAdd(&pos64[(e >> 16) & 63u], 1);
            sorted_src[p] = (unsigned short)(e & 0xFFFFu);
        }
    }
}

// ------- per-node factors + y = bf16(dinv * x) (one float4 -> ushort4) ------
__global__ void k_finalize(const int* __restrict__ count, const float* __restrict__ x,
                           float* __restrict__ scale, unsigned short* __restrict__ y,
                           int N) {
    int t = blockIdx.x * blockDim.x + threadIdx.x;   // over N*16 float4s
    if (t >= N * 16) return;
    int v = t >> 4;
    float dg = (float)(count[v] + 1);                // +1 self loop
    float dv = rsqrtf(dg);
    if ((t & 15) == 0) scale[v] = dv / dg;           // dinv[v]/deg[v]
    float4 xv = ((const float4*)x)[t];
    ushort4 o;
    o.x = f2bf(xv.x * dv); o.y = f2bf(xv.y * dv);
    o.z = f2bf(xv.z * dv); o.w = f2bf(xv.w * dv);
    ((ushort4*)y)[t] = o;
}

// ---------------- gather: agg_out[v] = scale[v] * (y[v] + sum y[src]) --------
__global__ __launch_bounds__(256) void k_gather(
        const unsigned short* __restrict__ y, const float* __restrict__ scale,
        const int* __restrict__ ptr, const int* __restrict__ count,
        const unsigned short* __restrict__ sorted_src,
        float* __restrict__ agg_out, int N) {
    int wave = threadIdx.x >> 6;
    int lane = threadIdx.x & 63;
    int vbase = blockIdx.x * 16 + wave * 4;

    for (int vi = 0; vi < 4; ++vi) {
        int v = vbase + vi;
        if (v >= N) return;
        int start = ptr[v];
        int cnt = count[v];
        float sc = scale[v];
        float a0 = bf2f(y[(size_t)v * NFEAT + lane]);   // self-loop term
        float a1 = 0.f, a2 = 0.f, a3 = 0.f, a4 = 0.f, a5 = 0.f, a6 = 0.f, a7 = 0.f;

        for (int c = 0; c < cnt; c += 64) {
            int m = min(64, cnt - c);
            int s_l = 0;
            if (lane < m) s_l = (int)sorted_src[start + c + lane];
            int j = 0;
            for (; j + 8 <= m; j += 8) {
                int s0 = __shfl(s_l, j + 0, 64), s1 = __shfl(s_l, j + 1, 64);
                int s2 = __shfl(s_l, j + 2, 64), s3 = __shfl(s_l, j + 3, 64);
                int s4 = __shfl(s_l, j + 4, 64), s5 = __shfl(s_l, j + 5, 64);
                int s6 = __shfl(s_l, j + 6, 64), s7 = __shfl(s_l, j + 7, 64);
                a0 += bf2f(y[(size_t)s0 * NFEAT + lane]);
                a1 += bf2f(y[(size_t)s1 * NFEAT + lane]);
                a2 += bf2f(y[(size_t)s2 * NFEAT + lane]);
                a3 += bf2f(y[(size_t)s3 * NFEAT + lane]);
                a4 += bf2f(y[(size_t)s4 * NFEAT + lane]);
                a5 += bf2f(y[(size_t)s5 * NFEAT + lane]);
                a6 += bf2f(y[(size_t)s6 * NFEAT + lane]);
                a7 += bf2f(y[(size_t)s7 * NFEAT + lane]);
            }
            for (; j < m; ++j) {
                int s0 = __shfl(s_l, j, 64);
                a0 += bf2f(y[(size_t)s0 * NFEAT + lane]);
            }
        }
        float a = ((a0 + a1) + (a2 + a3)) + ((a4 + a5) + (a6 + a7));
        agg_out[(size_t)v * NFEAT + lane] = a * sc;
    }
}

// ------- transpose W1,W2 into WT[2][64][64]: WT[m][c][k] = Wm[k][c] ---------
__global__ __launch_bounds__(256) void k_wt(const float* __restrict__ W1,
                                            const float* __restrict__ W2,
                                            float* __restrict__ WT) {
    int t = blockIdx.x * 256 + threadIdx.x;
    if (t < NFEAT * NFEAT) {
        int k = t >> 6, c = t & 63;
        WT[(size_t)c * NFEAT + k] = W1[t];
        WT[NFEAT * NFEAT + (size_t)c * NFEAT + k] = W2[t];
    }
}

// ------- epilogue v3: lane = node, NO aliasing, float4 stores ----------------
// R11 lessons: (1) in-place io forced per-c reloads (VGPR=36) -> read agg
// (separate __restrict__ buffer), write out; ar[64] stays in VGPRs.
// (2) scalar 4B stores at 256B lane stride shipped a full line each (233MB)
// -> build float4 per 4 columns (all statically unrolled), 8 clustered
// float4 stores per half-row combine in L2. 2-way column split doubles waves.
__global__ __launch_bounds__(256) void k_epi3(
        const float* __restrict__ agg, const float* __restrict__ WT,
        float* __restrict__ out, int N) {
    int gw = (blockIdx.x * 256 + threadIdx.x) >> 6;   // global wave id
    int lane = threadIdx.x & 63;
    int grp = gw >> 1;
    int ch = gw & 1;                                  // column half
    int v = grp * 64 + lane;
    if (v >= N) return;

    const float4* a4 = (const float4*)agg;
    float ar[NFEAT];
#pragma unroll
    for (int i = 0; i < NFEAT / 4; ++i) {
        float4 q = a4[(size_t)v * (NFEAT / 4) + i];
        ar[4 * i + 0] = q.x; ar[4 * i + 1] = q.y;
        ar[4 * i + 2] = q.z; ar[4 * i + 3] = q.w;
    }
    float4* o4 = (float4*)out;
#pragma unroll
    for (int g = 0; g < 8; ++g) {
        float res[4];
#pragma unroll
        for (int cc = 0; cc < 4; ++cc) {
            int c = ch * 32 + g * 4 + cc;
            const float* __restrict__ w1c = WT + (size_t)c * NFEAT;
            const float* __restrict__ w2c = WT + NFEAT * NFEAT + (size_t)c * NFEAT;
            float acc1 = 0.f, acc2 = 0.f;
#pragma unroll
            for (int k = 0; k < NFEAT; ++k) {
                acc1 = fmaf(ar[k], w1c[k], acc1);
                acc2 = fmaf(ar[k], w2c[k], acc2);
            }
            res[cc] = fmaxf(acc1, 0.0f) * (1.0f / (1.0f + __expf(-acc2)));
        }
        float4 q;
        q.x = res[0]; q.y = res[1]; q.z = res[2]; q.w = res[3];
        o4[(size_t)v * (NFEAT / 4) + ch * 8 + g] = q;
    }
}

// ------- fallback epilogue (R10 proven): shfl GEMM in place on d_out ---------
__global__ __launch_bounds__(256) void k_epi(
        float* __restrict__ io, const float* __restrict__ W1,
        const float* __restrict__ W2, int N) {
    __shared__ float w1[NFEAT * NFEAT];
    __shared__ float w2[NFEAT * NFEAT];
    for (int i = threadIdx.x; i < NFEAT * NFEAT; i += 256) {
        w1[i] = W1[i];
        w2[i] = W2[i];
    }
    __syncthreads();
    int wave = threadIdx.x >> 6;
    int lane = threadIdx.x & 63;
    for (int v = blockIdx.x * 4 + wave; v < N; v += gridDim.x * 4) {
        float a = io[(size_t)v * NFEAT + lane];
        float acc1 = 0.0f, acc2 = 0.0f;
#pragma unroll
        for (int k = 0; k < NFEAT; ++k) {
            float ak = __shfl(a, k, 64);
            acc1 = fmaf(ak, w1[k * NFEAT + lane], acc1);
            acc2 = fmaf(ak, w2[k * NFEAT + lane], acc2);
        }
        float x1 = fmaxf(acc1, 0.0f);
        float x2 = 1.0f / (1.0f + __expf(-acc2));
        io[(size_t)v * NFEAT + lane] = x1 * x2;
    }
}

extern "C" void kernel_launch(void* const* d_in, const int* in_sizes, int n_in,
                              void* d_out, int out_size, void* d_ws, size_t ws_size,
                              hipStream_t stream) {
    const float* x  = (const float*)d_in[0];
    const int*   ei = (const int*)d_in[1];
    const float* W1 = (const float*)d_in[2];
    const float* W2 = (const float*)d_in[3];
    float* out = (float*)d_out;

    const int N = in_sizes[0] / NFEAT;       // 50000 (<= 65536: edge packing)
    const int E = in_sizes[1] / 2;           // 1,600,000
    const int nb = (N + BNODES - 1) / BNODES;   // 782 buckets

    // workspace layout (256B-aligned slices)
    char* ws = (char*)d_ws;
    size_t off = 0;
    auto alloc = [&](size_t bytes) {
        char* p = ws + off;
        off = (off + bytes + 255) & ~(size_t)255;
        return p;
    };
    int*   count  = (int*)alloc((size_t)N * 4);
    float* scale  = (float*)alloc((size_t)N * 4);
    int*   ptr    = (int*)alloc((size_t)N * 4);
    int*   bcnt   = (int*)alloc((size_t)MAXBUCK * 4);
    int*   bstart = (int*)alloc((size_t)(MAXBUCK + 1) * 4);
    int*   bfill  = (int*)alloc((size_t)MAXBUCK * 4);
    float* WT     = (float*)alloc((size_t)2 * NFEAT * NFEAT * 4);

    // T1 layout: agg (f32, N*64) OVERLAYS the edges region (disjoint
    // lifetimes: edges dies at k_sort2, agg born at k_gather).
    size_t aggB   = (size_t)N * NFEAT * 4;
    size_t edgeB  = (size_t)E * 4;
    size_t regB   = aggB > edgeB ? aggB : edgeB;
    size_t t1_need = off + regB + (size_t)N * NFEAT * 2 + (size_t)E * 2 + 1024;

    hipMemsetAsync(bcnt, 0, (size_t)MAXBUCK * 4, stream);
    k_wt<<<(NFEAT * NFEAT + 255) / 256, 256, 0, stream>>>(W1, W2, WT);
    k_histb<<<256, 256, 0, stream>>>(ei, bcnt, E, nb);
    k_bscan<<<1, 1024, 0, stream>>>(bcnt, bstart, bfill, nb, E);
    int gpart = (E + 1024 * KPT - 1) / (1024 * KPT);

    if (ws_size >= t1_need) {
        // ---- T1: separate agg, alias-free register epilogue ----
        char* reg = (char*)alloc(regB);
        unsigned int*   edges      = (unsigned int*)reg;
        float*          agg        = (float*)reg;
        unsigned short* y          = (unsigned short*)alloc((size_t)N * NFEAT * 2);
        unsigned short* sorted_src = (unsigned short*)alloc((size_t)E * 2);

        k_part<<<gpart, 1024, 0, stream>>>(ei, bfill, edges, E, nb);
        k_sort2<false><<<nb, 256, 0, stream>>>(edges, bstart, count, ptr,
                                               sorted_src, N, E);
        k_finalize<<<(N * 16 + 255) / 256, 256, 0, stream>>>(count, x, scale, y, N);
        k_gather<<<(N + 15) / 16, 256, 0, stream>>>(y, scale, ptr, count,
                                                    sorted_src, agg, N);
        int nwaves = ((N + 63) / 64) * 2;          // 2-way column split
        k_epi3<<<(nwaves + 3) / 4, 256, 0, stream>>>(agg, WT, out, N);
    } else {
        // ---- T2: R10 fallback (agg in d_out, shfl epilogue in place) ----
        unsigned int*   edges = (unsigned int*)alloc(edgeB);
        unsigned short* y     = (unsigned short*)alloc((size_t)N * NFEAT * 2);
        unsigned short* sorted_src;
        bool inplace;
        if (ws_size >= off + (size_t)E * 2) {
            sorted_src = (unsigned short*)alloc((size_t)E * 2);
            inplace = false;
        } else {
            sorted_src = (unsigned short*)edges;
            inplace = true;
        }
        k_part<<<gpart, 1024, 0, stream>>>(ei, bfill, edges, E, nb);
        if (inplace) {
            k_sort2<true><<<nb, 256, 0, stream>>>(edges, bstart, count, ptr,
                                                  sorted_src, N, E);
        } else {
            k_sort2<false><<<nb, 256, 0, stream>>>(edges, bstart, count, ptr,
                                                   sorted_src, N, E);
        }
        k_finalize<<<(N * 16 + 255) / 256, 256, 0, stream>>>(count, x, scale, y, N);
        k_gather<<<(N + 15) / 16, 256, 0, stream>>>(y, scale, ptr, count,
                                                    sorted_src, out, N);
        k_epi<<<512, 256, 0, stream>>>(out, W1, W2, N);
    }
}

// Round 13
// 140.269 us; speedup vs baseline: 1.1883x; 1.1883x over previous
//
#include <hip/hip_runtime.h>

#define NFEAT 64
#define BNODES 64            // nodes per dst-bucket (bucket = dst >> 6)
#define MAXBUCK 1024         // supports N <= 65536 (edge packing needs N <= 65536)
#define SORT_LDS 6144        // whole-bucket LDS staging for in-place sort path
#define KPT 4                // edges per thread in k_part (register-staged)
#define NPW 16               // nodes per wave in k_epi4

__device__ __forceinline__ int load_idx(const int* __restrict__ ei, long long elem, int is64) {
    return is64 ? ei[2 * elem] : ei[(int)elem];
}

// bf16 round-to-nearest-even-ish (RN with tie bump; fine for finite data)
__device__ __forceinline__ unsigned short f2bf(float f) {
    unsigned int u = __float_as_uint(f);
    return (unsigned short)((u + 0x7FFFu + ((u >> 16) & 1u)) >> 16);
}
__device__ __forceinline__ float bf2f(unsigned short h) {
    return __uint_as_float(((unsigned int)h) << 16);
}

// ------- bucket-level histogram (782 counters; LDS hist + merge) ------------
// Self-detects int64 vs int32 edge encoding: values < 65536, so under int64
// every odd int32 word is 0 (probe 256 odd words; all-zero => int64).
__global__ __launch_bounds__(256) void k_histb(
        const int* __restrict__ ei, int* __restrict__ bcnt, int E, int nb) {
    __shared__ int h[MAXBUCK];
    __shared__ int s_not64;
    if (threadIdx.x == 0) s_not64 = 0;
    for (int i = threadIdx.x; i < nb; i += 256) h[i] = 0;
    __syncthreads();
    if (ei[2 * threadIdx.x + 1] != 0) s_not64 = 1;   // benign same-value race
    __syncthreads();
    int is64 = s_not64 ? 0 : 1;
    int per = (E + gridDim.x - 1) / gridDim.x;
    int e0 = blockIdx.x * per;
    int e1 = min(e0 + per, E);
    for (int i = e0 + threadIdx.x; i < e1; i += 256) {
        int d = load_idx(ei, (long long)E + i, is64);
        atomicAdd(&h[d >> 6], 1);
    }
    __syncthreads();
    for (int i = threadIdx.x; i < nb; i += 256)
        if (h[i]) atomicAdd(&bcnt[i], h[i]);
}

// ------- exclusive scan of bucket counts (+ sentinel) ------------------------
__global__ void k_bscan(const int* __restrict__ bcnt, int* __restrict__ bstart,
                        int* __restrict__ bfill, int nb, int E) {
    __shared__ int s[1024];
    int t = threadIdx.x;
    int mine = (t < nb) ? bcnt[t] : 0;
    s[t] = mine;
    __syncthreads();
    for (int off = 1; off < 1024; off <<= 1) {
        int v = (t >= off) ? s[t - off] : 0;
        __syncthreads();
        s[t] += v;
        __syncthreads();
    }
    if (t < nb) {
        int excl = s[t] - mine;
        bstart[t] = excl;
        bfill[t] = excl;
    }
    if (t == 0) bstart[nb] = E;   // sentinel
}

// ------- partition edges into dst-buckets, packed as (dst<<16)|src -----------
// Register-staged: each thread owns <= KPT edges, packs them once (no second
// global read of edge_index). 3-phase: LDS hist -> reserve chunks -> scatter.
__global__ __launch_bounds__(1024) void k_part(
        const int* __restrict__ ei, int* __restrict__ bfill,
        unsigned int* __restrict__ edges, int E, int nb) {
    __shared__ int h[MAXBUCK];
    __shared__ int chunk[MAXBUCK];
    __shared__ int cur[MAXBUCK];
    __shared__ int s_not64;
    if (threadIdx.x == 0) s_not64 = 0;
    for (int i = threadIdx.x; i < nb; i += 1024) h[i] = 0;
    __syncthreads();
    if (threadIdx.x < 256 && ei[2 * threadIdx.x + 1] != 0) s_not64 = 1;
    __syncthreads();
    int is64 = s_not64 ? 0 : 1;
    int per = (E + gridDim.x - 1) / gridDim.x;   // per <= 1024*KPT by grid calc
    int e0 = blockIdx.x * per;
    int e1 = min(e0 + per, E);

    unsigned int ed[KPT];
#pragma unroll
    for (int k = 0; k < KPT; ++k) {
        int i = e0 + threadIdx.x + k * 1024;
        if (i < e1) {
            unsigned int s = (unsigned int)load_idx(ei, i, is64);
            unsigned int d = (unsigned int)load_idx(ei, (long long)E + i, is64);
            ed[k] = (d << 16) | s;
            atomicAdd(&h[d >> 6], 1);
        }
    }
    __syncthreads();
    for (int i = threadIdx.x; i < nb; i += 1024) {
        int c = h[i];
        chunk[i] = c ? atomicAdd(&bfill[i], c) : 0;
        cur[i] = 0;
    }
    __syncthreads();
#pragma unroll
    for (int k = 0; k < KPT; ++k) {
        int i = e0 + threadIdx.x + k * 1024;
        if (i < e1) {
            int b = (int)(ed[k] >> 22);          // = dst >> 6
            int r = atomicAdd(&cur[b], 1);
            edges[chunk[b] + r] = ed[k];
        }
    }
}

// ------- per-bucket counting sort into ushort CSR + per-node count/ptr -------
// One block per bucket. LDS histogram doubles as per-node degree (count[v])
// and, scanned, as the CSR row pointer (ptr[v]).
template <bool INPLACE>
__global__ __launch_bounds__(256) void k_sort2(
        const unsigned int* __restrict__ edges, const int* __restrict__ bstart,
        int* __restrict__ count, int* __restrict__ ptr,
        unsigned short* __restrict__ sorted_src, int N, int E) {
    __shared__ int cnt64[BNODES];
    __shared__ int pos64[BNODES];
    __shared__ unsigned int raw[INPLACE ? SORT_LDS : 1];
    int tid = threadIdx.x;
    int vbase = blockIdx.x * BNODES;
    int es = bstart[blockIdx.x];
    int ee = bstart[blockIdx.x + 1];
    int m = ee - es;
    if (tid < BNODES) cnt64[tid] = 0;
    __syncthreads();

    if (INPLACE) {
        int mm = min(m, SORT_LDS);
        for (int i = tid; i < mm; i += 256) {
            unsigned int e = edges[es + i];
            raw[i] = e;
            atomicAdd(&cnt64[(e >> 16) & 63u], 1);
        }
        for (int i = SORT_LDS + tid; i < m; i += 256)
            atomicAdd(&cnt64[(edges[es + i] >> 16) & 63u], 1);
    } else {
        for (int i = tid; i < m; i += 256)
            atomicAdd(&cnt64[(edges[es + i] >> 16) & 63u], 1);
    }
    __syncthreads();

    if (tid < BNODES) {                      // wave 0: 64-wide exclusive scan
        int c = cnt64[tid];
        int inc = c;
#pragma unroll
        for (int d = 1; d < 64; d <<= 1) {
            int t2 = __shfl_up(inc, d, 64);
            if (tid >= d) inc += t2;
        }
        int off = inc - c;
        pos64[tid] = es + off;
        int v = vbase + tid;
        if (v < N) {
            count[v] = c;
            ptr[v] = es + off;
        }
    }
    __syncthreads();

    if (INPLACE) {
        int mm = min(m, SORT_LDS);
        for (int i = tid; i < mm; i += 256) {
            unsigned int e = raw[i];
            int p = atomicAdd(&pos64[(e >> 16) & 63u], 1);
            sorted_src[p] = (unsigned short)(e & 0xFFFFu);
        }
        for (int i = SORT_LDS + tid; i < m; i += 256) {   // overflow: ~never
            unsigned int e = edges[es + i];
            int p = atomicAdd(&pos64[(e >> 16) & 63u], 1);
            sorted_src[p] = (unsigned short)(e & 0xFFFFu);
        }
    } else {
        for (int i = tid; i < m; i += 256) {
            unsigned int e = edges[es + i];
            int p = atomicAdd(&pos64[(e >> 16) & 63u], 1);
            sorted_src[p] = (unsigned short)(e & 0xFFFFu);
        }
    }
}

// ------- per-node factors + y = bf16(dinv * x) (one float4 -> ushort4) ------
__global__ void k_finalize(const int* __restrict__ count, const float* __restrict__ x,
                           float* __restrict__ scale, unsigned short* __restrict__ y,
                           int N) {
    int t = blockIdx.x * blockDim.x + threadIdx.x;   // over N*16 float4s
    if (t >= N * 16) return;
    int v = t >> 4;
    float dg = (float)(count[v] + 1);                // +1 self loop
    float dv = rsqrtf(dg);
    if ((t & 15) == 0) scale[v] = dv / dg;           // dinv[v]/deg[v]
    float4 xv = ((const float4*)x)[t];
    ushort4 o;
    o.x = f2bf(xv.x * dv); o.y = f2bf(xv.y * dv);
    o.z = f2bf(xv.z * dv); o.w = f2bf(xv.w * dv);
    ((ushort4*)y)[t] = o;
}

// ---------------- gather: agg_out[v] = scale[v] * (y[v] + sum y[src]) --------
__global__ __launch_bounds__(256) void k_gather(
        const unsigned short* __restrict__ y, const float* __restrict__ scale,
        const int* __restrict__ ptr, const int* __restrict__ count,
        const unsigned short* __restrict__ sorted_src,
        float* __restrict__ agg_out, int N) {
    int wave = threadIdx.x >> 6;
    int lane = threadIdx.x & 63;
    int vbase = blockIdx.x * 16 + wave * 4;

    for (int vi = 0; vi < 4; ++vi) {
        int v = vbase + vi;
        if (v >= N) return;
        int start = ptr[v];
        int cnt = count[v];
        float sc = scale[v];
        float a0 = bf2f(y[(size_t)v * NFEAT + lane]);   // self-loop term
        float a1 = 0.f, a2 = 0.f, a3 = 0.f, a4 = 0.f, a5 = 0.f, a6 = 0.f, a7 = 0.f;

        for (int c = 0; c < cnt; c += 64) {
            int m = min(64, cnt - c);
            int s_l = 0;
            if (lane < m) s_l = (int)sorted_src[start + c + lane];
            int j = 0;
            for (; j + 8 <= m; j += 8) {
                int s0 = __shfl(s_l, j + 0, 64), s1 = __shfl(s_l, j + 1, 64);
                int s2 = __shfl(s_l, j + 2, 64), s3 = __shfl(s_l, j + 3, 64);
                int s4 = __shfl(s_l, j + 4, 64), s5 = __shfl(s_l, j + 5, 64);
                int s6 = __shfl(s_l, j + 6, 64), s7 = __shfl(s_l, j + 7, 64);
                a0 += bf2f(y[(size_t)s0 * NFEAT + lane]);
                a1 += bf2f(y[(size_t)s1 * NFEAT + lane]);
                a2 += bf2f(y[(size_t)s2 * NFEAT + lane]);
                a3 += bf2f(y[(size_t)s3 * NFEAT + lane]);
                a4 += bf2f(y[(size_t)s4 * NFEAT + lane]);
                a5 += bf2f(y[(size_t)s5 * NFEAT + lane]);
                a6 += bf2f(y[(size_t)s6 * NFEAT + lane]);
                a7 += bf2f(y[(size_t)s7 * NFEAT + lane]);
            }
            for (; j < m; ++j) {
                int s0 = __shfl(s_l, j, 64);
                a0 += bf2f(y[(size_t)s0 * NFEAT + lane]);
            }
        }
        float a = ((a0 + a1) + (a2 + a3)) + ((a4 + a5) + (a6 + a7));
        agg_out[(size_t)v * NFEAT + lane] = a * sc;
    }
}

// ------- epilogue v4: weights in VGPRs, a-row via uniform broadcast loads ----
// R11/R12 lessons: shfl-GEMM = DS-bound; in-place = alias reloads; per-lane
// uniform weight loads = VMEM-bound. Here lane = output column, w1r/w2r
// (128 VGPRs, statically indexed via full unroll) are loaded ONCE per wave
// (coalesced); per node: 16 uniform float4 loads (1 L2 request each) +
// 128 FMAs in 4 chains + one coalesced 256B row store.
__global__ __launch_bounds__(256) void k_epi4(
        const float* __restrict__ agg, const float* __restrict__ W1,
        const float* __restrict__ W2, float* __restrict__ out, int N) {
    int gw = (blockIdx.x * 256 + threadIdx.x) >> 6;   // global wave id
    int lane = threadIdx.x & 63;
    float w1r[NFEAT], w2r[NFEAT];
#pragma unroll
    for (int k = 0; k < NFEAT; ++k) {
        w1r[k] = W1[k * NFEAT + lane];   // coalesced: lane-consecutive
        w2r[k] = W2[k * NFEAT + lane];
    }
    int v0 = gw * NPW;
    int v1 = min(v0 + NPW, N);
    for (int v = v0; v < v1; ++v) {
        const float4* ar = (const float4*)(agg + (size_t)v * NFEAT);
        float acc1a = 0.f, acc1b = 0.f, acc2a = 0.f, acc2b = 0.f;
#pragma unroll
        for (int q = 0; q < NFEAT / 4; ++q) {
            float4 a4 = ar[q];               // wave-uniform address
            acc1a = fmaf(a4.x, w1r[4 * q + 0], acc1a);
            acc1b = fmaf(a4.y, w1r[4 * q + 1], acc1b);
            acc2a = fmaf(a4.x, w2r[4 * q + 0], acc2a);
            acc2b = fmaf(a4.y, w2r[4 * q + 1], acc2b);
            acc1a = fmaf(a4.z, w1r[4 * q + 2], acc1a);
            acc1b = fmaf(a4.w, w1r[4 * q + 3], acc1b);
            acc2a = fmaf(a4.z, w2r[4 * q + 2], acc2a);
            acc2b = fmaf(a4.w, w2r[4 * q + 3], acc2b);
        }
        float x1 = fmaxf(acc1a + acc1b, 0.0f);
        float x2 = 1.0f / (1.0f + __expf(-(acc2a + acc2b)));
        out[(size_t)v * NFEAT + lane] = x1 * x2;   // coalesced 256B row
    }
}

// ------- fallback epilogue (R10 proven): shfl GEMM in place on d_out ---------
__global__ __launch_bounds__(256) void k_epi(
        float* __restrict__ io, const float* __restrict__ W1,
        const float* __restrict__ W2, int N) {
    __shared__ float w1[NFEAT * NFEAT];
    __shared__ float w2[NFEAT * NFEAT];
    for (int i = threadIdx.x; i < NFEAT * NFEAT; i += 256) {
        w1[i] = W1[i];
        w2[i] = W2[i];
    }
    __syncthreads();
    int wave = threadIdx.x >> 6;
    int lane = threadIdx.x & 63;
    for (int v = blockIdx.x * 4 + wave; v < N; v += gridDim.x * 4) {
        float a = io[(size_t)v * NFEAT + lane];
        float acc1 = 0.0f, acc2 = 0.0f;
#pragma unroll
        for (int k = 0; k < NFEAT; ++k) {
            float ak = __shfl(a, k, 64);
            acc1 = fmaf(ak, w1[k * NFEAT + lane], acc1);
            acc2 = fmaf(ak, w2[k * NFEAT + lane], acc2);
        }
        float x1 = fmaxf(acc1, 0.0f);
        float x2 = 1.0f / (1.0f + __expf(-acc2));
        io[(size_t)v * NFEAT + lane] = x1 * x2;
    }
}

extern "C" void kernel_launch(void* const* d_in, const int* in_sizes, int n_in,
                              void* d_out, int out_size, void* d_ws, size_t ws_size,
                              hipStream_t stream) {
    const float* x  = (const float*)d_in[0];
    const int*   ei = (const int*)d_in[1];
    const float* W1 = (const float*)d_in[2];
    const float* W2 = (const float*)d_in[3];
    float* out = (float*)d_out;

    const int N = in_sizes[0] / NFEAT;       // 50000 (<= 65536: edge packing)
    const int E = in_sizes[1] / 2;           // 1,600,000
    const int nb = (N + BNODES - 1) / BNODES;   // 782 buckets

    // workspace layout (256B-aligned slices)
    char* ws = (char*)d_ws;
    size_t off = 0;
    auto alloc = [&](size_t bytes) {
        char* p = ws + off;
        off = (off + bytes + 255) & ~(size_t)255;
        return p;
    };
    int*   count  = (int*)alloc((size_t)N * 4);
    float* scale  = (float*)alloc((size_t)N * 4);
    int*   ptr    = (int*)alloc((size_t)N * 4);
    int*   bcnt   = (int*)alloc((size_t)MAXBUCK * 4);
    int*   bstart = (int*)alloc((size_t)(MAXBUCK + 1) * 4);
    int*   bfill  = (int*)alloc((size_t)MAXBUCK * 4);

    // T1 layout: agg (f32, N*64) OVERLAYS the edges region (disjoint
    // lifetimes: edges dies at k_sort2, agg born at k_gather).
    size_t aggB   = (size_t)N * NFEAT * 4;
    size_t edgeB  = (size_t)E * 4;
    size_t regB   = aggB > edgeB ? aggB : edgeB;
    size_t t1_need = off + regB + (size_t)N * NFEAT * 2 + (size_t)E * 2 + 1024;

    hipMemsetAsync(bcnt, 0, (size_t)MAXBUCK * 4, stream);
    k_histb<<<256, 256, 0, stream>>>(ei, bcnt, E, nb);
    k_bscan<<<1, 1024, 0, stream>>>(bcnt, bstart, bfill, nb, E);
    int gpart = (E + 1024 * KPT - 1) / (1024 * KPT);

    if (ws_size >= t1_need) {
        // ---- T1: separate agg, weights-in-VGPR register epilogue ----
        char* reg = (char*)alloc(regB);
        unsigned int*   edges      = (unsigned int*)reg;
        float*          agg        = (float*)reg;
        unsigned short* y          = (unsigned short*)alloc((size_t)N * NFEAT * 2);
        unsigned short* sorted_src = (unsigned short*)alloc((size_t)E * 2);

        k_part<<<gpart, 1024, 0, stream>>>(ei, bfill, edges, E, nb);
        k_sort2<false><<<nb, 256, 0, stream>>>(edges, bstart, count, ptr,
                                               sorted_src, N, E);
        k_finalize<<<(N * 16 + 255) / 256, 256, 0, stream>>>(count, x, scale, y, N);
        k_gather<<<(N + 15) / 16, 256, 0, stream>>>(y, scale, ptr, count,
                                                    sorted_src, agg, N);
        int nwaves = (N + NPW - 1) / NPW;
        k_epi4<<<(nwaves + 3) / 4, 256, 0, stream>>>(agg, W1, W2, out, N);
    } else {
        // ---- T2: R10 fallback (agg in d_out, shfl epilogue in place) ----
        unsigned int*   edges = (unsigned int*)alloc(edgeB);
        unsigned short* y     = (unsigned short*)alloc((size_t)N * NFEAT * 2);
        unsigned short* sorted_src;
        bool inplace;
        if (ws_size >= off + (size_t)E * 2) {
            sorted_src = (unsigned short*)alloc((size_t)E * 2);
            inplace = false;
        } else {
            sorted_src = (unsigned short*)edges;
            inplace = true;
        }
        k_part<<<gpart, 1024, 0, stream>>>(ei, bfill, edges, E, nb);
        if (inplace) {
            k_sort2<true><<<nb, 256, 0, stream>>>(edges, bstart, count, ptr,
                                                  sorted_src, N, E);
        } else {
            k_sort2<false><<<nb, 256, 0, stream>>>(edges, bstart, count, ptr,
                                                   sorted_src, N, E);
        }
        k_finalize<<<(N * 16 + 255) / 256, 256, 0, stream>>>(count, x, scale, y, N);
        k_gather<<<(N + 15) / 16, 256, 0, stream>>>(y, scale, ptr, count,
                                                    sorted_src, out, N);
        k_epi<<<512, 256, 0, stream>>>(out, W1, W2, N);
    }
}

// Round 14
// 139.698 us; speedup vs baseline: 1.1931x; 1.0041x over previous
//
#include <hip/hip_runtime.h>

#define NFEAT 64
#define BNODES 64            // nodes per dst-bucket (bucket = dst >> 6)
#define MAXBUCK 1024         // supports N <= 65536 (edge packing needs N <= 65536)
#define SORT_LDS 6144        // whole-bucket LDS staging for in-place sort path
#define KPT 4                // edges per thread in k_part (register-staged)
#define NPW 16               // nodes per wave in k_epi4

__device__ __forceinline__ int load_idx(const int* __restrict__ ei, long long elem, int is64) {
    return is64 ? ei[2 * elem] : ei[(int)elem];
}

// bf16 round-to-nearest-even-ish (RN with tie bump; fine for finite data)
__device__ __forceinline__ unsigned short f2bf(float f) {
    unsigned int u = __float_as_uint(f);
    return (unsigned short)((u + 0x7FFFu + ((u >> 16) & 1u)) >> 16);
}
__device__ __forceinline__ float bf2f(unsigned short h) {
    return __uint_as_float(((unsigned int)h) << 16);
}

// ------- zero bcnt (replaces hipMemsetAsync; one tiny block) ----------------
__global__ void k_zero(int* __restrict__ p, int n) {
    for (int i = threadIdx.x; i < n; i += 1024) p[i] = 0;
}

// ------- bucket-level histogram (782 counters; LDS hist + merge) ------------
// Self-detects int64 vs int32 edge encoding: values < 65536, so under int64
// every odd int32 word is 0 (probe 256 odd words; all-zero => int64).
__global__ __launch_bounds__(256) void k_histb(
        const int* __restrict__ ei, int* __restrict__ bcnt, int E, int nb) {
    __shared__ int h[MAXBUCK];
    __shared__ int s_not64;
    if (threadIdx.x == 0) s_not64 = 0;
    for (int i = threadIdx.x; i < nb; i += 256) h[i] = 0;
    __syncthreads();
    if (ei[2 * threadIdx.x + 1] != 0) s_not64 = 1;   // benign same-value race
    __syncthreads();
    int is64 = s_not64 ? 0 : 1;
    int per = (E + gridDim.x - 1) / gridDim.x;
    int e0 = blockIdx.x * per;
    int e1 = min(e0 + per, E);
    for (int i = e0 + threadIdx.x; i < e1; i += 256) {
        int d = load_idx(ei, (long long)E + i, is64);
        atomicAdd(&h[d >> 6], 1);
    }
    __syncthreads();
    for (int i = threadIdx.x; i < nb; i += 256)
        if (h[i]) atomicAdd(&bcnt[i], h[i]);
}

// ------- exclusive scan of bucket counts (+ sentinel) ------------------------
__global__ void k_bscan(const int* __restrict__ bcnt, int* __restrict__ bstart,
                        int* __restrict__ bfill, int nb, int E) {
    __shared__ int s[1024];
    int t = threadIdx.x;
    int mine = (t < nb) ? bcnt[t] : 0;
    s[t] = mine;
    __syncthreads();
    for (int off = 1; off < 1024; off <<= 1) {
        int v = (t >= off) ? s[t - off] : 0;
        __syncthreads();
        s[t] += v;
        __syncthreads();
    }
    if (t < nb) {
        int excl = s[t] - mine;
        bstart[t] = excl;
        bfill[t] = excl;
    }
    if (t == 0) bstart[nb] = E;   // sentinel
}

// ------- partition edges into dst-buckets, packed as (dst<<16)|src -----------
// Register-staged: each thread owns <= KPT edges, packs them once (no second
// global read of edge_index). 3-phase: LDS hist -> reserve chunks -> scatter.
__global__ __launch_bounds__(1024) void k_part(
        const int* __restrict__ ei, int* __restrict__ bfill,
        unsigned int* __restrict__ edges, int E, int nb) {
    __shared__ int h[MAXBUCK];
    __shared__ int chunk[MAXBUCK];
    __shared__ int cur[MAXBUCK];
    __shared__ int s_not64;
    if (threadIdx.x == 0) s_not64 = 0;
    for (int i = threadIdx.x; i < nb; i += 1024) h[i] = 0;
    __syncthreads();
    if (threadIdx.x < 256 && ei[2 * threadIdx.x + 1] != 0) s_not64 = 1;
    __syncthreads();
    int is64 = s_not64 ? 0 : 1;
    int per = (E + gridDim.x - 1) / gridDim.x;   // per <= 1024*KPT by grid calc
    int e0 = blockIdx.x * per;
    int e1 = min(e0 + per, E);

    unsigned int ed[KPT];
#pragma unroll
    for (int k = 0; k < KPT; ++k) {
        int i = e0 + threadIdx.x + k * 1024;
        if (i < e1) {
            unsigned int s = (unsigned int)load_idx(ei, i, is64);
            unsigned int d = (unsigned int)load_idx(ei, (long long)E + i, is64);
            ed[k] = (d << 16) | s;
            atomicAdd(&h[d >> 6], 1);
        }
    }
    __syncthreads();
    for (int i = threadIdx.x; i < nb; i += 1024) {
        int c = h[i];
        chunk[i] = c ? atomicAdd(&bfill[i], c) : 0;
        cur[i] = 0;
    }
    __syncthreads();
#pragma unroll
    for (int k = 0; k < KPT; ++k) {
        int i = e0 + threadIdx.x + k * 1024;
        if (i < e1) {
            int b = (int)(ed[k] >> 22);          // = dst >> 6
            int r = atomicAdd(&cur[b], 1);
            edges[chunk[b] + r] = ed[k];
        }
    }
}

// ------- per-bucket counting sort into ushort CSR + per-node count/ptr -------
// One block per bucket. LDS histogram doubles as per-node degree (count[v])
// and, scanned, as the CSR row pointer (ptr[v]).
template <bool INPLACE>
__global__ __launch_bounds__(256) void k_sort2(
        const unsigned int* __restrict__ edges, const int* __restrict__ bstart,
        int* __restrict__ count, int* __restrict__ ptr,
        unsigned short* __restrict__ sorted_src, int N, int E) {
    __shared__ int cnt64[BNODES];
    __shared__ int pos64[BNODES];
    __shared__ unsigned int raw[INPLACE ? SORT_LDS : 1];
    int tid = threadIdx.x;
    int vbase = blockIdx.x * BNODES;
    int es = bstart[blockIdx.x];
    int ee = bstart[blockIdx.x + 1];
    int m = ee - es;
    if (tid < BNODES) cnt64[tid] = 0;
    __syncthreads();

    if (INPLACE) {
        int mm = min(m, SORT_LDS);
        for (int i = tid; i < mm; i += 256) {
            unsigned int e = edges[es + i];
            raw[i] = e;
            atomicAdd(&cnt64[(e >> 16) & 63u], 1);
        }
        for (int i = SORT_LDS + tid; i < m; i += 256)
            atomicAdd(&cnt64[(edges[es + i] >> 16) & 63u], 1);
    } else {
        for (int i = tid; i < m; i += 256)
            atomicAdd(&cnt64[(edges[es + i] >> 16) & 63u], 1);
    }
    __syncthreads();

    if (tid < BNODES) {                      // wave 0: 64-wide exclusive scan
        int c = cnt64[tid];
        int inc = c;
#pragma unroll
        for (int d = 1; d < 64; d <<= 1) {
            int t2 = __shfl_up(inc, d, 64);
            if (tid >= d) inc += t2;
        }
        int off = inc - c;
        pos64[tid] = es + off;
        int v = vbase + tid;
        if (v < N) {
            count[v] = c;
            ptr[v] = es + off;
        }
    }
    __syncthreads();

    if (INPLACE) {
        int mm = min(m, SORT_LDS);
        for (int i = tid; i < mm; i += 256) {
            unsigned int e = raw[i];
            int p = atomicAdd(&pos64[(e >> 16) & 63u], 1);
            sorted_src[p] = (unsigned short)(e & 0xFFFFu);
        }
        for (int i = SORT_LDS + tid; i < m; i += 256) {   // overflow: ~never
            unsigned int e = edges[es + i];
            int p = atomicAdd(&pos64[(e >> 16) & 63u], 1);
            sorted_src[p] = (unsigned short)(e & 0xFFFFu);
        }
    } else {
        for (int i = tid; i < m; i += 256) {
            unsigned int e = edges[es + i];
            int p = atomicAdd(&pos64[(e >> 16) & 63u], 1);
            sorted_src[p] = (unsigned short)(e & 0xFFFFu);
        }
    }
}

// ------- per-node factors + y = bf16(dinv * x) (one float4 -> ushort4) ------
__global__ void k_finalize(const int* __restrict__ count, const float* __restrict__ x,
                           float* __restrict__ scale, unsigned short* __restrict__ y,
                           int N) {
    int t = blockIdx.x * blockDim.x + threadIdx.x;   // over N*16 float4s
    if (t >= N * 16) return;
    int v = t >> 4;
    float dg = (float)(count[v] + 1);                // +1 self loop
    float dv = rsqrtf(dg);
    if ((t & 15) == 0) scale[v] = dv / dg;           // dinv[v]/deg[v]
    float4 xv = ((const float4*)x)[t];
    ushort4 o;
    o.x = f2bf(xv.x * dv); o.y = f2bf(xv.y * dv);
    o.z = f2bf(xv.z * dv); o.w = f2bf(xv.w * dv);
    ((ushort4*)y)[t] = o;
}

// ---------------- gather: agg_out[v] = scale[v] * (y[v] + sum y[src]) --------
__global__ __launch_bounds__(256) void k_gather(
        const unsigned short* __restrict__ y, const float* __restrict__ scale,
        const int* __restrict__ ptr, const int* __restrict__ count,
        const unsigned short* __restrict__ sorted_src,
        float* __restrict__ agg_out, int N) {
    int wave = threadIdx.x >> 6;
    int lane = threadIdx.x & 63;
    int vbase = blockIdx.x * 16 + wave * 4;

    for (int vi = 0; vi < 4; ++vi) {
        int v = vbase + vi;
        if (v >= N) return;
        int start = ptr[v];
        int cnt = count[v];
        float sc = scale[v];
        float a0 = bf2f(y[(size_t)v * NFEAT + lane]);   // self-loop term
        float a1 = 0.f, a2 = 0.f, a3 = 0.f, a4 = 0.f, a5 = 0.f, a6 = 0.f, a7 = 0.f;

        for (int c = 0; c < cnt; c += 64) {
            int m = min(64, cnt - c);
            int s_l = 0;
            if (lane < m) s_l = (int)sorted_src[start + c + lane];
            int j = 0;
            for (; j + 8 <= m; j += 8) {
                int s0 = __shfl(s_l, j + 0, 64), s1 = __shfl(s_l, j + 1, 64);
                int s2 = __shfl(s_l, j + 2, 64), s3 = __shfl(s_l, j + 3, 64);
                int s4 = __shfl(s_l, j + 4, 64), s5 = __shfl(s_l, j + 5, 64);
                int s6 = __shfl(s_l, j + 6, 64), s7 = __shfl(s_l, j + 7, 64);
                a0 += bf2f(y[(size_t)s0 * NFEAT + lane]);
                a1 += bf2f(y[(size_t)s1 * NFEAT + lane]);
                a2 += bf2f(y[(size_t)s2 * NFEAT + lane]);
                a3 += bf2f(y[(size_t)s3 * NFEAT + lane]);
                a4 += bf2f(y[(size_t)s4 * NFEAT + lane]);
                a5 += bf2f(y[(size_t)s5 * NFEAT + lane]);
                a6 += bf2f(y[(size_t)s6 * NFEAT + lane]);
                a7 += bf2f(y[(size_t)s7 * NFEAT + lane]);
            }
            for (; j < m; ++j) {
                int s0 = __shfl(s_l, j, 64);
                a0 += bf2f(y[(size_t)s0 * NFEAT + lane]);
            }
        }
        float a = ((a0 + a1) + (a2 + a3)) + ((a4 + a5) + (a6 + a7));
        agg_out[(size_t)v * NFEAT + lane] = a * sc;
    }
}

// ------- epilogue v4b: weights in VGPRs, launch_bounds(256,1) ---------------
// R13 lesson: default regalloc targets ~6 waves/SIMD -> 84 VGPRs -> weights
// reloaded from global per node (VMEM-bound, 46us). min-waves=1 releases the
// budget so w1r/w2r (128 regs, statically indexed) stay resident. Per node:
// 16 uniform float4 loads + 128 FMAs (4 chains) + 1 coalesced 256B store.
__global__ __launch_bounds__(256, 1) void k_epi4(
        const float* __restrict__ agg, const float* __restrict__ W1,
        const float* __restrict__ W2, float* __restrict__ out, int N) {
    int gw = (blockIdx.x * 256 + threadIdx.x) >> 6;   // global wave id
    int lane = threadIdx.x & 63;
    float w1r[NFEAT], w2r[NFEAT];
#pragma unroll
    for (int k = 0; k < NFEAT; ++k) {
        w1r[k] = W1[k * NFEAT + lane];   // coalesced: lane-consecutive
        w2r[k] = W2[k * NFEAT + lane];
    }
    int v0 = gw * NPW;
    int v1 = min(v0 + NPW, N);
    for (int v = v0; v < v1; ++v) {
        const float4* ar = (const float4*)(agg + (size_t)v * NFEAT);
        float acc1a = 0.f, acc1b = 0.f, acc2a = 0.f, acc2b = 0.f;
#pragma unroll
        for (int q = 0; q < NFEAT / 4; ++q) {
            float4 a4 = ar[q];               // wave-uniform address
            acc1a = fmaf(a4.x, w1r[4 * q + 0], acc1a);
            acc1b = fmaf(a4.y, w1r[4 * q + 1], acc1b);
            acc2a = fmaf(a4.x, w2r[4 * q + 0], acc2a);
            acc2b = fmaf(a4.y, w2r[4 * q + 1], acc2b);
            acc1a = fmaf(a4.z, w1r[4 * q + 2], acc1a);
            acc1b = fmaf(a4.w, w1r[4 * q + 3], acc1b);
            acc2a = fmaf(a4.z, w2r[4 * q + 2], acc2a);
            acc2b = fmaf(a4.w, w2r[4 * q + 3], acc2b);
        }
        float x1 = fmaxf(acc1a + acc1b, 0.0f);
        float x2 = 1.0f / (1.0f + __expf(-(acc2a + acc2b)));
        out[(size_t)v * NFEAT + lane] = x1 * x2;   // coalesced 256B row
    }
}

// ------- fallback epilogue (R10 proven): shfl GEMM in place on d_out ---------
__global__ __launch_bounds__(256) void k_epi(
        float* __restrict__ io, const float* __restrict__ W1,
        const float* __restrict__ W2, int N) {
    __shared__ float w1[NFEAT * NFEAT];
    __shared__ float w2[NFEAT * NFEAT];
    for (int i = threadIdx.x; i < NFEAT * NFEAT; i += 256) {
        w1[i] = W1[i];
        w2[i] = W2[i];
    }
    __syncthreads();
    int wave = threadIdx.x >> 6;
    int lane = threadIdx.x & 63;
    for (int v = blockIdx.x * 4 + wave; v < N; v += gridDim.x * 4) {
        float a = io[(size_t)v * NFEAT + lane];
        float acc1 = 0.0f, acc2 = 0.0f;
#pragma unroll
        for (int k = 0; k < NFEAT; ++k) {
            float ak = __shfl(a, k, 64);
            acc1 = fmaf(ak, w1[k * NFEAT + lane], acc1);
            acc2 = fmaf(ak, w2[k * NFEAT + lane], acc2);
        }
        float x1 = fmaxf(acc1, 0.0f);
        float x2 = 1.0f / (1.0f + __expf(-acc2));
        io[(size_t)v * NFEAT + lane] = x1 * x2;
    }
}

extern "C" void kernel_launch(void* const* d_in, const int* in_sizes, int n_in,
                              void* d_out, int out_size, void* d_ws, size_t ws_size,
                              hipStream_t stream) {
    const float* x  = (const float*)d_in[0];
    const int*   ei = (const int*)d_in[1];
    const float* W1 = (const float*)d_in[2];
    const float* W2 = (const float*)d_in[3];
    float* out = (float*)d_out;

    const int N = in_sizes[0] / NFEAT;       // 50000 (<= 65536: edge packing)
    const int E = in_sizes[1] / 2;           // 1,600,000
    const int nb = (N + BNODES - 1) / BNODES;   // 782 buckets

    // workspace layout (256B-aligned slices)
    char* ws = (char*)d_ws;
    size_t off = 0;
    auto alloc = [&](size_t bytes) {
        char* p = ws + off;
        off = (off + bytes + 255) & ~(size_t)255;
        return p;
    };
    int*   count  = (int*)alloc((size_t)N * 4);
    float* scale  = (float*)alloc((size_t)N * 4);
    int*   ptr    = (int*)alloc((size_t)N * 4);
    int*   bcnt   = (int*)alloc((size_t)MAXBUCK * 4);
    int*   bstart = (int*)alloc((size_t)(MAXBUCK + 1) * 4);
    int*   bfill  = (int*)alloc((size_t)MAXBUCK * 4);

    // T1 layout: agg (f32, N*64) OVERLAYS the edges region (disjoint
    // lifetimes: edges dies at k_sort2, agg born at k_gather).
    size_t aggB   = (size_t)N * NFEAT * 4;
    size_t edgeB  = (size_t)E * 4;
    size_t regB   = aggB > edgeB ? aggB : edgeB;
    size_t t1_need = off + regB + (size_t)N * NFEAT * 2 + (size_t)E * 2 + 1024;

    k_zero<<<1, 1024, 0, stream>>>(bcnt, MAXBUCK);
    k_histb<<<256, 256, 0, stream>>>(ei, bcnt, E, nb);
    k_bscan<<<1, 1024, 0, stream>>>(bcnt, bstart, bfill, nb, E);
    int gpart = (E + 1024 * KPT - 1) / (1024 * KPT);

    if (ws_size >= t1_need) {
        // ---- T1: separate agg, weights-in-VGPR register epilogue ----
        char* reg = (char*)alloc(regB);
        unsigned int*   edges      = (unsigned int*)reg;
        float*          agg        = (float*)reg;
        unsigned short* y          = (unsigned short*)alloc((size_t)N * NFEAT * 2);
        unsigned short* sorted_src = (unsigned short*)alloc((size_t)E * 2);

        k_part<<<gpart, 1024, 0, stream>>>(ei, bfill, edges, E, nb);
        k_sort2<false><<<nb, 256, 0, stream>>>(edges, bstart, count, ptr,
                                               sorted_src, N, E);
        k_finalize<<<(N * 16 + 255) / 256, 256, 0, stream>>>(count, x, scale, y, N);
        k_gather<<<(N + 15) / 16, 256, 0, stream>>>(y, scale, ptr, count,
                                                    sorted_src, agg, N);
        int nwaves = (N + NPW - 1) / NPW;
        k_epi4<<<(nwaves + 3) / 4, 256, 0, stream>>>(agg, W1, W2, out, N);
    } else {
        // ---- T2: R10 fallback (agg in d_out, shfl epilogue in place) ----
        unsigned int*   edges = (unsigned int*)alloc(edgeB);
        unsigned short* y     = (unsigned short*)alloc((size_t)N * NFEAT * 2);
        unsigned short* sorted_src;
        bool inplace;
        if (ws_size >= off + (size_t)E * 2) {
            sorted_src = (unsigned short*)alloc((size_t)E * 2);
            inplace = false;
        } else {
            sorted_src = (unsigned short*)edges;
            inplace = true;
        }
        k_part<<<gpart, 1024, 0, stream>>>(ei, bfill, edges, E, nb);
        if (inplace) {
            k_sort2<true><<<nb, 256, 0, stream>>>(edges, bstart, count, ptr,
                                                  sorted_src, N, E);
        } else {
            k_sort2<false><<<nb, 256, 0, stream>>>(edges, bstart, count, ptr,
                                                   sorted_src, N, E);
        }
        k_finalize<<<(N * 16 + 255) / 256, 256, 0, stream>>>(count, x, scale, y, N);
        k_gather<<<(N + 15) / 16, 256, 0, stream>>>(y, scale, ptr, count,
                                                    sorted_src, out, N);
        k_epi<<<512, 256, 0, stream>>>(out, W1, W2, N);
    }
}